// Round 20
// baseline (357.955 us; speedup 1.0000x reference)
//
#include <hip/hip_runtime.h>

// KNN top-16: B=4, N=M=8192, C=3.  (GOLD METRIC LOCKED by R17, absmax=0:
//   norms = (x²+z²)+y² [hsum, plain]; cross = fma(z,z',fma(y,y',x*x'));
//   d2 = max((q2+r2) - 2*cross, 0); stable (d2,idx) ascending; 0-based.)
// R20: issue-bound attack. Each thread serves TWO queries (A, B=A+32) on the
// same ref subset: one ds_read_b128 feeds 2 evals; metric computed 2-wide
// packed (ext_vector float2 + __builtin_elementwise_fma -> v_pk_fma_f32),
// elementwise-rounded == bit-identical to the scalar gold chain. Appends
// still recompute the exact scalar metric at compact (tile live).
// Shared per-query screen thresholds via 8-lane shuffle-min (conservative).

#define TPB 256
#define QPB 64   // queries per block (32 A + 32 B)
#define SPL 8    // threads per query
#define KK 16
#define TILE_PTS 512
#define CAP 16   // LDS candidate slots per thread per queue
#define TRIG 8   // compaction trigger (checked every 8; 7+8 <= 16)

typedef float v2f __attribute__((ext_vector_type(2)));

__global__ __launch_bounds__(TPB, 4) void knn_topk_kernel(
    const float* __restrict__ ref, const float* __restrict__ query,
    float* __restrict__ dout, float* __restrict__ iout, int N, int M) {
#pragma clang fp contract(off)
  __shared__ float4 tile[TILE_PTS];              // 8 KB: x,y,z,r2
  __shared__ unsigned short siA[CAP * TPB];      // 8 KB: queue A (local idx)
  __shared__ unsigned short siB[CAP * TPB];      // 8 KB: queue B
  __shared__ float md[KK * TPB];                 // 16 KB: merge staging

  const int tid = threadIdx.x;
  const int h = tid & (SPL - 1);
  const int qidA = blockIdx.x * QPB + (tid >> 3);
  const int qidB = qidA + 32;                    // same batch (8192 % 64 == 0)
  const int b = qidA / M;

  const float* qpA = query + (size_t)qidA * 3;
  const float* qpB = query + (size_t)qidB * 3;
  const float qxA = qpA[0], qyA = qpA[1], qzA = qpA[2];
  const float qxB = qpB[0], qyB = qpB[1], qzB = qpB[2];
  // HSUM norm: (x2 + z2) + y2
  const float q2A = (qxA * qxA + qzA * qzA) + qyA * qyA;
  const float q2B = (qxB * qxB + qzB * qzB) + qyB * qyB;
  const v2f qxv = {qxA, qxB}, qyv = {qyA, qyB}, qzv = {qzA, qzB};
  const v2f q2v = {q2A, q2B};
  const v2f m2v = {-2.0f, -2.0f};

  float aA[KK], aB[KK];
  int aiA[KK], aiB[KK];
#pragma unroll
  for (int s = 0; s < KK; ++s) {
    aA[s] = 3.0e38f; aiA[s] = 0; aB[s] = 3.0e38f; aiB[s] = 0;
  }
  float TA = 3.0e38f, TB = 3.0e38f;  // shared screens (min over 8 lanes)
  int cntA = 0, cntB = 0;

  const float* refb = ref + (size_t)b * N * 3;

  // Stable insert into sorted-ascending list (after equals).
  auto ins = [&](float (&a)[KK], int (&ai)[KK], float d, int ix) {
    bool pc = false;
    float pa = 0.f;
    int pi = 0;
#pragma unroll
    for (int s = 0; s < KK; ++s) {
      float oa = a[s];
      int oi = ai[s];
      bool c = d < oa;
      a[s] = c ? (pc ? pa : d) : oa;
      ai[s] = c ? (pc ? pi : ix) : oi;
      pc = c;
      pa = oa;
      pi = oi;
    }
  };

  // Exact scalar recompute (bit-identical to packed halves) + insert.
  auto compactQ = [&](unsigned short* si, int& cnt, float (&a)[KK],
                      int (&ai)[KK], int tbase, float qx, float qy, float qz,
                      float q2) {
    int cm = cnt;
    for (int s = 0; s < cm; ++s) {
      int loc = si[s * TPB + tid];
      float4 p = tile[loc];
      float cr = qx * p.x;
      cr = __builtin_fmaf(qy, p.y, cr);
      cr = __builtin_fmaf(qz, p.z, cr);
      float s2 = q2 + p.w;
      float d2 = __builtin_fmaf(-2.0f, cr, s2);
      float d2c = d2 < 0.f ? 0.f : d2;
      if (d2c < a[KK - 1]) ins(a, ai, d2c, tbase + loc);
    }
    cnt = 0;
  };

  auto wmin8 = [&](float x) {  // min over the 8 lanes of this query group
    float m = fminf(x, __shfl_xor(x, 1));
    m = fminf(m, __shfl_xor(m, 2));
    return fminf(m, __shfl_xor(m, 4));
  };

  const int ntiles = N / TILE_PTS;
  for (int t = 0; t < ntiles; ++t) {
    __syncthreads();
    {
      // Stage 512 points; r2 = HSUM norm (x2+z2)+y2.
      int pl = tid * 2;
      const float* rp = refb + (size_t)(t * TILE_PTS + pl) * 3;
#pragma unroll
      for (int u = 0; u < 2; ++u) {
        float rx = rp[3 * u + 0];
        float ry = rp[3 * u + 1];
        float rz = rp[3 * u + 2];
        float r2 = (rx * rx + rz * rz) + ry * ry;
        tile[pl + u] = make_float4(rx, ry, rz, r2);
      }
    }
    __syncthreads();
    const int tbase = t * TILE_PTS;
    for (int g = 0; g < TILE_PTS / SPL; g += 8) {
#pragma unroll
      for (int u = 0; u < 8; ++u) {
        const int loc = (g + u) * SPL + h;  // subset h: refs ≡ h (mod 8)
        float4 p = tile[loc];
        // Packed 2-query metric; elementwise rounding == scalar gold chain.
        v2f cr = qxv * p.x;
        cr = __builtin_elementwise_fma(qyv, (v2f){p.y, p.y}, cr);
        cr = __builtin_elementwise_fma(qzv, (v2f){p.z, p.z}, cr);
        v2f s2 = q2v + (v2f){p.w, p.w};
        v2f d2 = __builtin_elementwise_fma(m2v, cr, s2);
        if (d2.x <= TA) {  // conservative shared screen (<= keeps ties)
          siA[cntA * TPB + tid] = (unsigned short)loc;
          cntA++;
        }
        if (d2.y <= TB) {
          siB[cntB * TPB + tid] = (unsigned short)loc;
          cntB++;
        }
      }
      if (__any(cntA >= TRIG) || __any(cntB >= TRIG)) {
        compactQ(siA, cntA, aA, aiA, tbase, qxA, qyA, qzA, q2A);
        compactQ(siB, cntB, aB, aiB, tbase, qxB, qyB, qzB, q2B);
        TA = wmin8(aA[KK - 1]);
        TB = wmin8(aB[KK - 1]);
      }
    }
    if (__any(cntA > 0) || __any(cntB > 0)) {  // tile retires: resolve now
      compactQ(siA, cntA, aA, aiA, tbase, qxA, qyA, qzA, q2A);
      compactQ(siB, cntB, aB, aiB, tbase, qxB, qyB, qzB, q2B);
      TA = wmin8(aA[KK - 1]);
      TB = wmin8(aB[KK - 1]);
    }
  }

  // Epilogue: two sequential 8-way merges (A then B), siA reused for idx.
  float* dq;
  float* iq;
#pragma unroll
  for (int s = 0; s < KK; ++s) {
    md[s * TPB + tid] = aA[s];
    siA[s * TPB + tid] = (unsigned short)aiA[s];
  }
  __syncthreads();
  if (h == 0) {
    int pp[SPL];
    float hd[SPL];
    int hi[SPL];
#pragma unroll
    for (int j = 0; j < SPL; ++j) {
      pp[j] = 0;
      hd[j] = md[tid + j];
      hi[j] = siA[tid + j];
    }
    dq = dout + (size_t)qidA * KK;
    iq = iout + (size_t)qidA * KK;
    for (int o = 0; o < KK; ++o) {
      int best = 0;
#pragma unroll
      for (int j = 1; j < SPL; ++j) {
        bool bt = (hd[j] < hd[best]) || (hd[j] == hd[best] && hi[j] < hi[best]);
        if (bt) best = j;
      }
      dq[o] = sqrtf(hd[best]);
      iq[o] = (float)hi[best];
      int np = pp[best] + 1;
      pp[best] = np;
      if (np < KK) {
        hd[best] = md[np * TPB + tid + best];
        hi[best] = siA[np * TPB + tid + best];
      } else {
        hd[best] = 3.0e38f;
      }
    }
  }
  __syncthreads();
#pragma unroll
  for (int s = 0; s < KK; ++s) {
    md[s * TPB + tid] = aB[s];
    siA[s * TPB + tid] = (unsigned short)aiB[s];
  }
  __syncthreads();
  if (h == 0) {
    int pp[SPL];
    float hd[SPL];
    int hi[SPL];
#pragma unroll
    for (int j = 0; j < SPL; ++j) {
      pp[j] = 0;
      hd[j] = md[tid + j];
      hi[j] = siA[tid + j];
    }
    dq = dout + (size_t)qidB * KK;
    iq = iout + (size_t)qidB * KK;
    for (int o = 0; o < KK; ++o) {
      int best = 0;
#pragma unroll
      for (int j = 1; j < SPL; ++j) {
        bool bt = (hd[j] < hd[best]) || (hd[j] == hd[best] && hi[j] < hi[best]);
        if (bt) best = j;
      }
      dq[o] = sqrtf(hd[best]);
      iq[o] = (float)hi[best];
      int np = pp[best] + 1;
      pp[best] = np;
      if (np < KK) {
        hd[best] = md[np * TPB + tid + best];
        hi[best] = siA[np * TPB + tid + best];
      } else {
        hd[best] = 3.0e38f;
      }
    }
  }
}

extern "C" void kernel_launch(void* const* d_in, const int* in_sizes, int n_in,
                              void* d_out, int out_size, void* d_ws, size_t ws_size,
                              hipStream_t stream) {
  const float* ref = (const float*)d_in[0];
  const float* query = (const float*)d_in[1];
  const int B = 4, C = 3;
  int N = in_sizes[0] / (B * C);
  int M = in_sizes[1] / (B * C);
  float* dout = (float*)d_out;
  float* iout = dout + (size_t)out_size / 2;  // idx half, written as float
  int totalQ = B * M;
  int blocks = totalQ / QPB;
  knn_topk_kernel<<<blocks, TPB, 0, stream>>>(ref, query, dout, iout, N, M);
}

// Round 21
// 298.874 us; speedup vs baseline: 1.1977x; 1.1977x over previous
//
#include <hip/hip_runtime.h>

// KNN top-16: B=4, N=M=8192, C=3.  (GOLD METRIC LOCKED by R17, absmax=0:
//   norms = (x²+z²)+y² [hsum, plain]; cross = fma(z,z',fma(y,y',x*x'));
//   d2 = max((q2+r2) - 2*cross, 0); stable (d2,idx) ascending; 0-based.)
// R21: R19 shape (1 query/thread, 4 blocks/CU) + POINT-PAIR packing.
// Tile stored pair-transposed: pair P = {x0,x1,y0,y1,z0,z1,w0,w1} (32B) so
// 2x ds_read_b128 feed v_pk_fma_f32 directly (no transpose movs). Packed
// lanes are independent IEEE f32 ops == bit-identical to scalar gold chain.
// Screen: fminf(d2.x,d2.y) <= T (T = 8-lane min of a[15], conservative);
// appends store tile-local point idx; compact recomputes exact scalar
// metric from the live tile (stable inserts, index-ascending scan order).

#define TPB 256
#define QPB 32   // queries per block
#define SPL 8    // threads per query
#define KK 16
#define TILE_PTS 512
#define NPAIR (TILE_PTS / 2)
#define CAP 24   // LDS candidate slots per thread (TRIG-1 + 16 <= CAP)
#define TRIG 8   // compaction trigger (checked every 8 pairs = 16 points)

typedef float v2f __attribute__((ext_vector_type(2)));

__global__ __launch_bounds__(TPB, 4) void knn_topk_kernel(
    const float* __restrict__ ref, const float* __restrict__ query,
    float* __restrict__ dout, float* __restrict__ iout, int N, int M) {
#pragma clang fp contract(off)
  __shared__ float tp[NPAIR * 8];                // 8 KB transposed pairs
  __shared__ unsigned short si[CAP * TPB];       // 12 KB: buffered local idx
  __shared__ float md[KK * TPB];                 // 16 KB: merge staging

  const int tid = threadIdx.x;
  const int h = tid & (SPL - 1);
  const int qid = blockIdx.x * QPB + (tid >> 3);
  const int b = qid / M;

  const float* qp = query + (size_t)qid * 3;
  const float qx = qp[0], qy = qp[1], qz = qp[2];
  // HSUM norm: (x2 + z2) + y2
  const float q2 = (qx * qx + qz * qz) + qy * qy;
  const v2f qxv = {qx, qx}, qyv = {qy, qy}, qzv = {qz, qz};
  const v2f q2v = {q2, q2};
  const v2f m2v = {-2.0f, -2.0f};

  float a[KK];
  int ai[KK];
#pragma unroll
  for (int s = 0; s < KK; ++s) { a[s] = 3.0e38f; ai[s] = 0; }
  float T = 3.0e38f;  // shared screen threshold (min of 8 lanes' a[15])
  int cnt = 0;

  const float* refb = ref + (size_t)b * N * 3;

  // Stable insert into sorted-ascending list (after equals).
  auto ins = [&](float d, int ix) {
    bool pc = false;
    float pa = 0.f;
    int pi = 0;
#pragma unroll
    for (int s = 0; s < KK; ++s) {
      float oa = a[s];
      int oi = ai[s];
      bool c = d < oa;
      a[s] = c ? (pc ? pa : d) : oa;
      ai[s] = c ? (pc ? pi : ix) : oi;
      pc = c;
      pa = oa;
      pi = oi;
    }
  };

  // Exact scalar recompute from live tile + insert + refresh shared T.
  // Wave-uniform call sites only (uses cross-lane shuffles).
  auto compact = [&](int tbase) {
    int cm = cnt;
    for (int s = 0; s < cm; ++s) {
      int loc = si[s * TPB + tid];
      int P = loc >> 1, e = loc & 1;
      const float* pb = &tp[P * 8];
      float px = pb[0 + e], py = pb[2 + e], pz = pb[4 + e], pw = pb[6 + e];
      float cr = qx * px;
      cr = __builtin_fmaf(qy, py, cr);
      cr = __builtin_fmaf(qz, pz, cr);
      float s2 = q2 + pw;
      float d2 = __builtin_fmaf(-2.0f, cr, s2);
      float d2c = d2 < 0.f ? 0.f : d2;
      if (d2c < a[KK - 1]) ins(d2c, tbase + loc);
    }
    cnt = 0;
    float a15 = a[KK - 1];
    float m = fminf(a15, __shfl_xor(a15, 1));
    m = fminf(m, __shfl_xor(m, 2));
    T = fminf(m, __shfl_xor(m, 4));
  };

  const int ntiles = N / TILE_PTS;
  for (int t = 0; t < ntiles; ++t) {
    __syncthreads();
    {
      // Stage pair P = tid: refs 2*tid, 2*tid+1; w = HSUM norm (x2+z2)+y2.
      const float* rp = refb + (size_t)(t * TILE_PTS + 2 * tid) * 3;
      float x0 = rp[0], y0 = rp[1], z0 = rp[2];
      float x1 = rp[3], y1 = rp[4], z1 = rp[5];
      float w0 = (x0 * x0 + z0 * z0) + y0 * y0;
      float w1 = (x1 * x1 + z1 * z1) + y1 * y1;
      float4* pb = (float4*)&tp[tid * 8];
      pb[0] = make_float4(x0, x1, y0, y1);
      pb[1] = make_float4(z0, z1, w0, w1);
    }
    __syncthreads();
    const int tbase = t * TILE_PTS;
    for (int g = 0; g < NPAIR / SPL; g += 8) {
#pragma unroll
      for (int u = 0; u < 8; ++u) {
        const int P = (g + u) * SPL + h;  // pair subset: P ≡ h (mod 8)
        const v2f* pb = (const v2f*)&tp[P * 8];
        v2f px = pb[0], py = pb[1], pz = pb[2], pw = pb[3];
        // Packed 2-point metric (v_pk_*): bit-identical per element.
        v2f cr = qxv * px;
        cr = __builtin_elementwise_fma(qyv, py, cr);
        cr = __builtin_elementwise_fma(qzv, pz, cr);
        v2f s2 = q2v + pw;
        v2f d2 = __builtin_elementwise_fma(m2v, cr, s2);
        if (fminf(d2.x, d2.y) <= T) {  // conservative pair screen
          int loc = P * 2;
          if (d2.x <= T) {
            si[cnt * TPB + tid] = (unsigned short)loc;
            cnt++;
          }
          if (d2.y <= T) {
            si[cnt * TPB + tid] = (unsigned short)(loc + 1);
            cnt++;
          }
        }
      }
      if (__any(cnt >= TRIG)) compact(tbase);  // wave-synchronized
    }
    if (__any(cnt > 0)) compact(tbase);  // tile retires: resolve local idxs
  }

  // Dump per-thread sorted lists to LDS (si doubles as mi), 8-way merge.
#pragma unroll
  for (int s = 0; s < KK; ++s) {
    md[s * TPB + tid] = a[s];
    si[s * TPB + tid] = (unsigned short)ai[s];
  }
  __syncthreads();
  if (h == 0) {
    int pp[SPL];
    float hd[SPL];
    int hi[SPL];
#pragma unroll
    for (int j = 0; j < SPL; ++j) {
      pp[j] = 0;
      hd[j] = md[tid + j];
      hi[j] = si[tid + j];
    }
    float* dq = dout + (size_t)qid * KK;
    float* iq = iout + (size_t)qid * KK;
    for (int o = 0; o < KK; ++o) {
      int best = 0;
#pragma unroll
      for (int j = 1; j < SPL; ++j) {
        bool bt = (hd[j] < hd[best]) || (hd[j] == hd[best] && hi[j] < hi[best]);
        if (bt) best = j;
      }
      dq[o] = sqrtf(hd[best]);
      iq[o] = (float)hi[best];  // 0-based
      int np = pp[best] + 1;
      pp[best] = np;
      if (np < KK) {
        hd[best] = md[np * TPB + tid + best];
        hi[best] = si[np * TPB + tid + best];
      } else {
        hd[best] = 3.0e38f;
      }
    }
  }
}

extern "C" void kernel_launch(void* const* d_in, const int* in_sizes, int n_in,
                              void* d_out, int out_size, void* d_ws, size_t ws_size,
                              hipStream_t stream) {
  const float* ref = (const float*)d_in[0];
  const float* query = (const float*)d_in[1];
  const int B = 4, C = 3;
  int N = in_sizes[0] / (B * C);
  int M = in_sizes[1] / (B * C);
  float* dout = (float*)d_out;
  float* iout = dout + (size_t)out_size / 2;  // idx half, written as float
  int totalQ = B * M;
  int blocks = totalQ / QPB;
  knn_topk_kernel<<<blocks, TPB, 0, stream>>>(ref, query, dout, iout, N, M);
}